// Round 19
// baseline (380.170 us; speedup 1.0000x reference)
//
#include <hip/hip_runtime.h>

#define NN 10000
#define NE 160000
static constexpr int TPB = 256;
static constexpr int SCAN_T = 1024;

typedef unsigned int uint32;

static __device__ __forceinline__ ushort f2bf(float f) {
  uint32 u = __float_as_uint(f);
  u += 0x7fff + ((u >> 16) & 1);   // round-to-nearest-even
  return (ushort)(u >> 16);
}
static __device__ __forceinline__ uint32 pk2bf(float a, float b) {
  return (uint32)f2bf(a) | ((uint32)f2bf(b) << 16);
}
static __device__ __forceinline__ float bflo(uint32 u) {
  return __uint_as_float(u << 16);
}
static __device__ __forceinline__ float bfhi(uint32 u) {
  return __uint_as_float(u & 0xffff0000u);
}
// acc += a.lo*b.lo + a.hi*b.hi  (packed bf16 pairs, f32 accumulate)
static __device__ __forceinline__ void dot2bf(float& acc, uint32 a, uint32 b) {
  asm("v_dot2_f32_bf16 %0, %1, %2, %0" : "+v"(acc) : "v"(a), "v"(b));
}

// ---------------- sort / CSR build ----------------

// cnt = [row counts (NN) | col counts (NN)] contiguous
__global__ void k_count(const int* __restrict__ ei, int* __restrict__ cnt) {
  int e = blockIdx.x * TPB + threadIdx.x;
  if (e >= NE) return;
  atomicAdd(&cnt[ei[e]], 1);
  atomicAdd(&cnt[NN + ei[NE + e]], 1);
}

// 16-wave block scan: block 0 -> row CSR, block 1 -> col CSR.
__global__ void __launch_bounds__(SCAN_T)
k_scan2(const int* __restrict__ cnt_all, int* __restrict__ off_r, int* __restrict__ cur_r,
        int* __restrict__ off_c, int* __restrict__ cur_c) {
  const int* cnt = (blockIdx.x == 0) ? cnt_all : cnt_all + NN;
  int* off = (blockIdx.x == 0) ? off_r : off_c;
  int* cur = (blockIdx.x == 0) ? cur_r : cur_c;
  __shared__ int s_wave[16];
  __shared__ int s_carry;
  int tid = threadIdx.x;
  int lane = tid & 63, wid = tid >> 6;
  if (tid == 0) s_carry = 0;
  __syncthreads();
  for (int base = 0; base < NN; base += SCAN_T) {
    int i = base + tid;
    int v = (i < NN) ? cnt[i] : 0;
    int s = v;
    #pragma unroll
    for (int d = 1; d < 64; d <<= 1) {
      int t = __shfl_up(s, d, 64);
      if (lane >= d) s += t;
    }
    if (lane == 63) s_wave[wid] = s;
    __syncthreads();
    if (wid == 0 && lane < 16) {
      int ws = s_wave[lane];
      #pragma unroll
      for (int d = 1; d < 16; d <<= 1) {
        int t = __shfl_up(ws, d, 64);
        if (lane >= d) ws += t;
      }
      s_wave[lane] = ws;   // inclusive wave-sum scan
    }
    __syncthreads();
    int waveoff = (wid > 0) ? s_wave[wid - 1] : 0;
    int excl = s_carry + waveoff + s - v;
    if (i < NN) { off[i] = excl; cur[i] = excl; }
    __syncthreads();   // all reads of s_carry/s_wave done
    if (tid == 0) s_carry += s_wave[15];
    __syncthreads();
  }
  if (tid == 0) off[NN] = s_carry;
}

__global__ void k_fill_row(const int* __restrict__ ei, int* __restrict__ cur_row,
                           int* __restrict__ eid_row) {
  int e = blockIdx.x * TPB + threadIdx.x;
  if (e >= NE) return;
  int r = ei[e];
  int p = atomicAdd(&cur_row[r], 1);
  eid_row[p] = e;
}

// colpos[s] = position of sorted-slot s in col-sorted order (direct, no inverse pass)
__global__ void k_fill_colpos(const int* __restrict__ ei, const int* __restrict__ eid_row,
                              int* __restrict__ cur_col, int* __restrict__ colpos) {
  int s = blockIdx.x * TPB + threadIdx.x;
  if (s >= NE) return;
  int e = eid_row[s];
  int c = ei[NE + e];
  int p = atomicAdd(&cur_col[c], 1);
  colpos[s] = p;
}

// ---------------- per-layer kernels ----------------

// xp = x@pw^T + pb ; root = xp@rw^T + cb ; B[n,o] = sum_i xp[i]*eb2[i*D+o]
template<int DIN, int D>
__global__ void __launch_bounds__(TPB)
k_nodeprep(const float* __restrict__ x, const float* __restrict__ pw, const float* __restrict__ pb,
           const float* __restrict__ rw, const float* __restrict__ cb, const float* __restrict__ eb2,
           float* __restrict__ xp, float* __restrict__ root, float* __restrict__ Bb) {
  __shared__ float s_pw[D * DIN], s_rw[D * D], s_eb2[D * D], s_pb[D], s_cb[D];
  for (int t = threadIdx.x; t < D * DIN; t += TPB) s_pw[t] = pw[t];
  for (int t = threadIdx.x; t < D * D; t += TPB) { s_rw[t] = rw[t]; s_eb2[t] = eb2[t]; }
  for (int t = threadIdx.x; t < D; t += TPB) { s_pb[t] = pb[t]; s_cb[t] = cb[t]; }
  __syncthreads();
  int n = blockIdx.x * TPB + threadIdx.x;
  if (n >= NN) return;
  float xv[DIN];
  const float4* x4 = (const float4*)(x + (size_t)n * DIN);
  #pragma unroll
  for (int i = 0; i < DIN / 4; i++) {
    float4 v = x4[i];
    xv[4*i+0] = v.x; xv[4*i+1] = v.y; xv[4*i+2] = v.z; xv[4*i+3] = v.w;
  }
  float xpv[D];
  #pragma unroll
  for (int o = 0; o < D; o++) {
    float a = s_pb[o];
    #pragma unroll
    for (int i = 0; i < DIN; i++) a = fmaf(s_pw[o*DIN + i], xv[i], a);
    xpv[o] = a;
    xp[(size_t)n*D + o] = a;
  }
  #pragma unroll
  for (int o = 0; o < D; o++) {
    float a = s_cb[o];
    #pragma unroll
    for (int i = 0; i < D; i++) a = fmaf(s_rw[o*D + i], xpv[i], a);
    root[(size_t)n*D + o] = a;
  }
  #pragma unroll
  for (int o = 0; o < D; o++) {
    float a = 0.f;
    #pragma unroll
    for (int i = 0; i < D; i++) a = fmaf(xpv[i], s_eb2[i*D + o], a);
    Bb[(size_t)n*D + o] = a;
  }
}

// h = relu(ea @ ew1^T + eb1) for all edges, bf16 k-pairs, row per sorted slot s:
// hg[s][k2] (64 words).  One block: 256 edges (8 barrier-free passes of 32).
__global__ void __launch_bounds__(TPB)
k_h(const int* __restrict__ eid_row, const float* __restrict__ ea,
    const float* __restrict__ ew1, const float* __restrict__ eb1,
    uint32* __restrict__ hg) {
  __shared__ __align__(16) uint32 s_w[4 * 128];   // packed ew1 i-pairs: [i2][k]
  __shared__ float s_b[128];
  int tid = threadIdx.x;
  for (int t = tid; t < 512; t += TPB) {
    int i2 = t >> 7, k = t & 127;
    s_w[t] = pk2bf(ew1[k * 8 + 2 * i2], ew1[k * 8 + 2 * i2 + 1]);
  }
  for (int t = tid; t < 128; t += TPB) s_b[t] = eb1[t];
  __syncthreads();
  int e2b = tid >> 3, k8 = tid & 7;
  int s0 = blockIdx.x * 256;
  #pragma unroll 2
  for (int pass = 0; pass < 8; pass++) {
    int s = s0 + pass * 32 + e2b;
    if (s >= NE) continue;
    const float2* eap = (const float2*)(ea + (size_t)eid_row[s] * 8);
    float2 v0 = eap[0], v1 = eap[1], v2 = eap[2], v3 = eap[3];
    uint32 ep0 = pk2bf(v0.x, v0.y);
    uint32 ep1 = pk2bf(v1.x, v1.y);
    uint32 ep2 = pk2bf(v2.x, v2.y);
    uint32 ep3 = pk2bf(v3.x, v3.y);
    __align__(16) uint32 outw[8];
    #pragma unroll
    for (int j = 0; j < 8; j++) {
      int k2 = k8 * 8 + j;
      float a0 = s_b[2 * k2], a1 = s_b[2 * k2 + 1];
      uint2 w0 = *(const uint2*)(s_w + 0 * 128 + 2 * k2);
      dot2bf(a0, ep0, w0.x); dot2bf(a1, ep0, w0.y);
      uint2 w1 = *(const uint2*)(s_w + 1 * 128 + 2 * k2);
      dot2bf(a0, ep1, w1.x); dot2bf(a1, ep1, w1.y);
      uint2 w2 = *(const uint2*)(s_w + 2 * 128 + 2 * k2);
      dot2bf(a0, ep2, w2.x); dot2bf(a1, ep2, w2.y);
      uint2 w3 = *(const uint2*)(s_w + 3 * 128 + 2 * k2);
      dot2bf(a0, ep3, w3.x); dot2bf(a1, ep3, w3.y);
      outw[j] = pk2bf(fmaxf(a0, 0.f), fmaxf(a1, 0.f));
    }
    uint4* dst = (uint4*)(hg + (size_t)s * 64 + k8 * 8);
    dst[0] = *(uint4*)&outw[0];
    dst[1] = *(uint4*)&outw[4];
  }
}

// Fused agg + next-layer nodeprep (layers 1..3), packed-bf16 msg input, NS k-splits.
template<int DP, int D, int NS>
__global__ void __launch_bounds__(TPB)
k_aggprep(const int* __restrict__ col_off,
          const uint32* __restrict__ m0, const uint32* __restrict__ m1,
          const uint32* __restrict__ m2, const uint32* __restrict__ m3,
          const float* __restrict__ root_prev, const float* __restrict__ xp_prev,
          const float* __restrict__ pw, const float* __restrict__ pb,
          const float* __restrict__ rw, const float* __restrict__ cb,
          const float* __restrict__ eb2,
          float* __restrict__ xp, float* __restrict__ root, float* __restrict__ Bb) {
  constexpr int W = DP / 2;      // packed words per edge
  constexpr int NB = TPB / W;    // nodes per block (16 for DP=32, 32 for DP=16)
  __shared__ float s_x[NB][DP];
  __shared__ float s_xpv[NB][D];
  __shared__ float s_pw[D * DP], s_rw[D * D], s_eb2[D * D], s_pb[D], s_cb[D];
  int tid = threadIdx.x;
  for (int t = tid; t < D * DP; t += TPB) s_pw[t] = pw[t];
  for (int t = tid; t < D * D; t += TPB) { s_rw[t] = rw[t]; s_eb2[t] = eb2[t]; }
  for (int t = tid; t < D; t += TPB) { s_pb[t] = pb[t]; s_cb[t] = cb[t]; }
  int g = tid / W, o2 = tid % W;
  int n = blockIdx.x * NB + g;
  if (n < NN) {
    int p0 = col_off[n], p1 = col_off[n + 1];
    float ax = 0.f, ay = 0.f;
    for (int p = p0; p < p1; p++) {
      uint32 w0 = m0[(size_t)p * W + o2];
      uint32 w1 = m1[(size_t)p * W + o2];
      ax += bflo(w0) + bflo(w1);
      ay += bfhi(w0) + bfhi(w1);
      if (NS > 2) {
        uint32 w2 = m2[(size_t)p * W + o2];
        uint32 w3 = m3[(size_t)p * W + o2];
        ax += bflo(w2) + bflo(w3);
        ay += bfhi(w2) + bfhi(w3);
      }
    }
    float deg = (p1 > p0) ? (float)(p1 - p0) : 1.f;
    float2 rp = *(const float2*)(root_prev + (size_t)n * DP + 2 * o2);
    float2 xq = *(const float2*)(xp_prev + (size_t)n * DP + 2 * o2);
    float c0 = ax / deg + rp.x, c1 = ay / deg + rp.y;
    s_x[g][2 * o2]     = (c0 > 0.f ? c0 : 0.f) + xq.x;
    s_x[g][2 * o2 + 1] = (c1 > 0.f ? c1 : 0.f) + xq.y;
  }
  __syncthreads();
  for (int t = tid; t < NB * D; t += TPB) {
    int g2 = t / D, o = t % D;
    int n2 = blockIdx.x * NB + g2;
    if (n2 < NN) {
      float a = s_pb[o];
      #pragma unroll
      for (int i = 0; i < DP; i++) a = fmaf(s_pw[o * DP + i], s_x[g2][i], a);
      s_xpv[g2][o] = a;
      xp[(size_t)n2 * D + o] = a;
    }
  }
  __syncthreads();
  for (int t = tid; t < NB * D; t += TPB) {
    int g2 = t / D, o = t % D;
    int n2 = blockIdx.x * NB + g2;
    if (n2 < NN) {
      float r2 = s_cb[o], b2 = 0.f;
      #pragma unroll
      for (int i = 0; i < D; i++) {
        r2 = fmaf(s_rw[o * D + i], s_xpv[g2][i], r2);
        b2 = fmaf(s_xpv[g2][i], s_eb2[i * D + o], b2);
      }
      root[(size_t)n2 * D + o] = r2;
      Bb[(size_t)n2 * D + o] = b2;
    }
  }
}

// All four layers' V transposes in one dispatch.
// Layout (words): l0 @0 (65536, D=32), l1 @65536, l2 @81920, l3 @98304 (16384 each, D=16)
__global__ void k_trans_all(const float* __restrict__ e0, const float* __restrict__ e1,
                            const float* __restrict__ e2, const float* __restrict__ e3,
                            uint32* __restrict__ Vp) {
  int t = blockIdx.x * TPB + threadIdx.x;
  const float* ew2; uint32* dst; int D, loc;
  if (t < 65536)       { ew2 = e0; dst = Vp;         D = 32; loc = t; }
  else if (t < 81920)  { ew2 = e1; dst = Vp + 65536; D = 16; loc = t - 65536; }
  else if (t < 98304)  { ew2 = e2; dst = Vp + 81920; D = 16; loc = t - 81920; }
  else if (t < 114688) { ew2 = e3; dst = Vp + 98304; D = 16; loc = t - 98304; }
  else return;
  int COLS = D * 128;
  int i2 = loc / COLS;
  int r = loc - i2 * COLS;
  int w = r >> 1, p = r & 1;
  int k2 = w / D, o = w - k2 * D;
  int k = 2 * k2 + p;
  float lo = ew2[((size_t)((2 * i2) * D + o)) * 128 + k];
  float hi = ew2[((size_t)((2 * i2 + 1) * D + o)) * 128 + k];
  dst[loc] = pk2bf(lo, hi);
}

// Fused, split-k over blockIdx.y (KS splits; kq = split index).
// Phase B: 1/KS of each U-row (packed bf16 k-pairs, word[k2loc*D+o], stride UP) into LDS.
// Phase C (barrier-free): per edge-lane, read h from hg (global, precomputed), PV vs
// LDS U, scatter bf16-packed to msg[kq][colpos[s]].
template<int D, int G, int KS>
__global__ void __launch_bounds__(TPB)
k_fused(const int* __restrict__ row_off, const int* __restrict__ colpos,
        const uint32* __restrict__ hg, const uint32* __restrict__ Vp,
        const float* __restrict__ xp, const float* __restrict__ Bb,
        uint32* __restrict__ m0, uint32* __restrict__ m1,
        uint32* __restrict__ m2, uint32* __restrict__ m3) {
  constexpr int OQ = D / 4;            // threads per edge
  constexpr int EB = TPB / OQ;         // edges per stride
  constexpr int COLS = D * 128;
  constexpr int UW = COLS / 2;         // u32 words per full U-row
  constexpr int UH = UW / KS;          // words per split U-row
  constexpr int UP = UH + 4;           // padded row stride (bank stagger, 16B-aligned)
  constexpr int CT = UH / TPB;         // words per thread
  constexpr int KL2 = 64 / KS;         // packed k-pair words per edge in this split

  __shared__ __align__(16) uint32 s_U[G * UP];      // packed bf16 k-pairs (split)
  __shared__ uint32 s_xp2[G][D / 2];                // packed xp i-pairs
  __shared__ float  s_B[G * D];
  __shared__ int    s_off[G + 1];

  int tid = threadIdx.x;
  int kq = blockIdx.y;
  int n0 = blockIdx.x * G;
  int GA = NN - n0; if (GA > G) GA = G;
  uint32* ms[4] = {m0, m1, m2, m3};
  uint32* msgHp = ms[kq];

  // ---- phase A: per-node vectors ----
  for (int t = tid; t < G * (D / 2); t += TPB) {
    int g = t / (D / 2), i2 = t % (D / 2);
    if (g < GA) {
      float2 v = *(const float2*)(xp + (size_t)(n0 + g) * D + 2 * i2);
      s_xp2[g][i2] = pk2bf(v.x, v.y);
    } else {
      s_xp2[g][i2] = 0;
    }
  }
  for (int t = tid; t < G * D; t += TPB) {
    int g = t / D, i = t % D;
    s_B[t] = (g < GA && kq == 0) ? Bb[(size_t)(n0 + g) * D + i] : 0.f;
  }
  if (tid <= GA) s_off[tid] = row_off[n0 + tid];
  __syncthreads();

  // ---- phase B: split U-rows into LDS via dot2 (CT words x G nodes / thread) ----
  {
    const uint2* Vp2 = (const uint2*)Vp;   // [i2][w] -> {p=0 word, p=1 word}
    float accLo[G][CT], accHi[G][CT];
    #pragma unroll
    for (int g = 0; g < G; g++)
      #pragma unroll
      for (int j = 0; j < CT; j++) { accLo[g][j] = 0.f; accHi[g][j] = 0.f; }
    #pragma unroll 2
    for (int i2 = 0; i2 < D / 2; i2++) {
      uint2 vv[CT];
      #pragma unroll
      for (int j = 0; j < CT; j++)
        vv[j] = Vp2[(size_t)i2 * UW + kq * UH + j * TPB + tid];
      #pragma unroll
      for (int g = 0; g < G; g++) {
        uint32 xg = s_xp2[g][i2];
        #pragma unroll
        for (int j = 0; j < CT; j++) {
          dot2bf(accLo[g][j], xg, vv[j].x);
          dot2bf(accHi[g][j], xg, vv[j].y);
        }
      }
    }
    #pragma unroll
    for (int g = 0; g < G; g++)
      #pragma unroll
      for (int j = 0; j < CT; j++)
        s_U[g * UP + j * TPB + tid] = pk2bf(accLo[g][j], accHi[g][j]);
  }
  __syncthreads();

  // ---- phase C (barrier-free): strided edge loop ----
  int p0 = s_off[0], p1 = s_off[GA];
  int el = tid / OQ, oq = tid % OQ;
  for (int s = p0 + el; s < p1; s += EB) {
    int g = 0;
    #pragma unroll
    for (int q = 1; q < G; q++) g += (q < GA && s >= s_off[q]) ? 1 : 0;
    const uint32* hp = hg + (size_t)s * 64 + kq * KL2;
    const uint32* up = s_U + g * UP + oq * 4;
    float a0 = 0.f, a1 = 0.f, a2 = 0.f, a3 = 0.f;
    #pragma unroll
    for (int k8 = 0; k8 < KL2 / 4; k8++) {
      uint4 hw = *(const uint4*)(hp + 4 * k8);   // global (broadcast across OQ lanes)
      uint4 u0 = *(const uint4*)(up + (4 * k8 + 0) * D);
      uint4 u1 = *(const uint4*)(up + (4 * k8 + 1) * D);
      uint4 u2 = *(const uint4*)(up + (4 * k8 + 2) * D);
      uint4 u3 = *(const uint4*)(up + (4 * k8 + 3) * D);
      dot2bf(a0, hw.x, u0.x); dot2bf(a1, hw.x, u0.y); dot2bf(a2, hw.x, u0.z); dot2bf(a3, hw.x, u0.w);
      dot2bf(a0, hw.y, u1.x); dot2bf(a1, hw.y, u1.y); dot2bf(a2, hw.y, u1.z); dot2bf(a3, hw.y, u1.w);
      dot2bf(a0, hw.z, u2.x); dot2bf(a1, hw.z, u2.y); dot2bf(a2, hw.z, u2.z); dot2bf(a3, hw.z, u2.w);
      dot2bf(a0, hw.w, u3.x); dot2bf(a1, hw.w, u3.y); dot2bf(a2, hw.w, u3.z); dot2bf(a3, hw.w, u3.w);
    }
    float4 b = ((const float4*)(s_B + g * D))[oq];
    uint2 om;
    om.x = pk2bf(a0 + b.x, a1 + b.y);
    om.y = pk2bf(a2 + b.z, a3 + b.w);
    ((uint2*)(msgHp + (size_t)colpos[s] * (D / 2)))[oq] = om;
  }
}

// last-layer aggregation (packed msg in, f32 x out for the final edge MLP)
template<int D, int NS>
__global__ void __launch_bounds__(TPB)
k_agg(const int* __restrict__ col_off,
      const uint32* __restrict__ m0, const uint32* __restrict__ m1,
      const float* __restrict__ root, const float* __restrict__ xp,
      float* __restrict__ xout) {
  constexpr int W = D / 2;
  constexpr int GP = TPB / W;
  int g = threadIdx.x / W, o2 = threadIdx.x % W;
  int n = blockIdx.x * GP + g;
  if (n >= NN) return;
  int p0 = col_off[n], p1 = col_off[n + 1];
  float ax = 0.f, ay = 0.f;
  for (int p = p0; p < p1; p++) {
    uint32 w0 = m0[(size_t)p * W + o2];
    uint32 w1 = m1[(size_t)p * W + o2];
    ax += bflo(w0) + bflo(w1);
    ay += bfhi(w0) + bfhi(w1);
  }
  float deg = (p1 > p0) ? (float)(p1 - p0) : 1.f;
  float2 rp = *(const float2*)(root + (size_t)n * D + 2 * o2);
  float2 xq = *(const float2*)(xp + (size_t)n * D + 2 * o2);
  float c0 = ax / deg + rp.x, c1 = ay / deg + rp.y;
  xout[(size_t)n * D + 2 * o2]     = (c0 > 0.f ? c0 : 0.f) + xq.x;
  xout[(size_t)n * D + 2 * o2 + 1] = (c1 > 0.f ? c1 : 0.f) + xq.y;
}

// final edge MLP: out = relu((x[row]+x[col]) @ mw0^T + mb0) @ mw1^T + mb1
__global__ void __launch_bounds__(TPB)
k_final(const int* __restrict__ ei, const float* __restrict__ x,
        const float* __restrict__ mw0, const float* __restrict__ mb0,
        const float* __restrict__ mw1, const float* __restrict__ mb1,
        float* __restrict__ out) {
  __shared__ float s_w0[256], s_b0[16], s_w1[16], s_b1;
  for (int t = threadIdx.x; t < 256; t += TPB) s_w0[t] = mw0[t];
  if (threadIdx.x < 16) { s_b0[threadIdx.x] = mb0[threadIdx.x]; s_w1[threadIdx.x] = mw1[threadIdx.x]; }
  if (threadIdx.x == 0) s_b1 = mb1[0];
  __syncthreads();
  int e = blockIdx.x * TPB + threadIdx.x;
  if (e >= NE) return;
  int r = ei[e], c = ei[NE + e];
  const float4* xr4 = (const float4*)(x + (size_t)r * 16);
  const float4* xc4 = (const float4*)(x + (size_t)c * 16);
  float er[16];
  #pragma unroll
  for (int q = 0; q < 4; q++) {
    float4 vr = xr4[q], vc = xc4[q];
    er[4*q+0] = vr.x + vc.x; er[4*q+1] = vr.y + vc.y;
    er[4*q+2] = vr.z + vc.z; er[4*q+3] = vr.w + vc.w;
  }
  float o = s_b1;
  #pragma unroll
  for (int j = 0; j < 16; j++) {
    float t = s_b0[j];
    #pragma unroll
    for (int k = 0; k < 16; k++) t = fmaf(er[k], s_w0[j * 16 + k], t);
    t = fmaxf(t, 0.f);
    o = fmaf(t, s_w1[j], o);
  }
  out[e] = o;
}

// ---------------- host side ----------------

struct LayerPtrs {
  const float *pw, *pb, *ew1, *eb1, *ew2, *eb2, *rw, *cb;
};

extern "C" void kernel_launch(void* const* d_in, const int* in_sizes, int n_in,
                              void* d_out, int out_size, void* d_ws, size_t ws_size,
                              hipStream_t stream) {
  (void)in_sizes; (void)n_in; (void)out_size; (void)ws_size;
  const float* x0 = (const float*)d_in[0];
  const float* ea = (const float*)d_in[1];
  const int* ei = (const int*)d_in[2];
  LayerPtrs L[4];
  for (int l = 0; l < 4; l++) {
    L[l].pw  = (const float*)d_in[3 + 8 * l];
    L[l].pb  = (const float*)d_in[4 + 8 * l];
    L[l].ew1 = (const float*)d_in[5 + 8 * l];
    L[l].eb1 = (const float*)d_in[6 + 8 * l];
    L[l].ew2 = (const float*)d_in[7 + 8 * l];
    L[l].eb2 = (const float*)d_in[8 + 8 * l];
    L[l].rw  = (const float*)d_in[9 + 8 * l];
    L[l].cb  = (const float*)d_in[10 + 8 * l];
  }
  const float* mw0 = (const float*)d_in[35];
  const float* mb0 = (const float*)d_in[36];
  const float* mw1 = (const float*)d_in[37];
  const float* mb1 = (const float*)d_in[38];
  float* out = (float*)d_out;

  char* w = (char*)d_ws;
  size_t off = 0;
  auto alloc = [&](size_t b) -> void* {
    void* p = w + off;
    off = (off + b + 255) & ~(size_t)255;
    return p;
  };
  int* cnt      = (int*)alloc(sizeof(int) * 2 * NN);   // [row | col]
  int* row_off  = (int*)alloc(sizeof(int) * (NN + 1));
  int* col_off  = (int*)alloc(sizeof(int) * (NN + 1));
  int* cur_row  = (int*)alloc(sizeof(int) * NN);
  int* cur_col  = (int*)alloc(sizeof(int) * NN);
  int* eid_row  = (int*)alloc(sizeof(int) * NE);
  int* colpos   = (int*)alloc(sizeof(int) * NE);
  float* xpA   = (float*)alloc(sizeof(float) * NN * 32);
  float* xpB   = (float*)alloc(sizeof(float) * NN * 32);
  float* rootA = (float*)alloc(sizeof(float) * NN * 32);
  float* rootB = (float*)alloc(sizeof(float) * NN * 32);
  float* Bb    = (float*)alloc(sizeof(float) * NN * 32);
  uint32* msg0 = (uint32*)alloc(sizeof(uint32) * NE * 16);
  uint32* msg1 = (uint32*)alloc(sizeof(uint32) * NE * 16);
  uint32* msg2 = (uint32*)alloc(sizeof(uint32) * NE * 16);
  uint32* msg3 = (uint32*)alloc(sizeof(uint32) * NE * 16);
  uint32* hg   = (uint32*)alloc(sizeof(uint32) * (size_t)NE * 64);  // 41 MB
  float* xfin  = (float*)alloc(sizeof(float) * NN * 16);
  uint32* Vp   = (uint32*)alloc(sizeof(uint32) * 114688);  // 448 KB, all layers

  hipMemsetAsync(cnt, 0, sizeof(int) * 2 * NN, stream);
  k_count<<<(NE + TPB - 1) / TPB, TPB, 0, stream>>>(ei, cnt);
  k_scan2<<<2, SCAN_T, 0, stream>>>(cnt, row_off, cur_row, col_off, cur_col);
  k_fill_row<<<(NE + TPB - 1) / TPB, TPB, 0, stream>>>(ei, cur_row, eid_row);
  k_fill_colpos<<<(NE + TPB - 1) / TPB, TPB, 0, stream>>>(ei, eid_row, cur_col, colpos);
  k_trans_all<<<(114688 + TPB - 1) / TPB, TPB, 0, stream>>>(
      L[0].ew2, L[1].ew2, L[2].ew2, L[3].ew2, Vp);

  const int HB = (NE + 255) / 256;
  // layer 0 (DIN=16, D=32), split-k = 4
  k_nodeprep<16, 32><<<(NN + TPB - 1) / TPB, TPB, 0, stream>>>(
      x0, L[0].pw, L[0].pb, L[0].rw, L[0].cb, L[0].eb2, xpA, rootA, Bb);
  k_h<<<HB, TPB, 0, stream>>>(eid_row, ea, L[0].ew1, L[0].eb1, hg);
  {
    dim3 gf((NN + 5) / 6, 4);
    k_fused<32, 6, 4><<<gf, TPB, 0, stream>>>(
        row_off, colpos, hg, Vp, xpA, Bb, msg0, msg1, msg2, msg3);
  }
  // layer 1 (DP=32 -> D=16), consumes 4 splits
  k_aggprep<32, 16, 4><<<(NN + 15) / 16, TPB, 0, stream>>>(
      col_off, msg0, msg1, msg2, msg3, rootA, xpA,
      L[1].pw, L[1].pb, L[1].rw, L[1].cb, L[1].eb2, xpB, rootB, Bb);
  k_h<<<HB, TPB, 0, stream>>>(eid_row, ea, L[1].ew1, L[1].eb1, hg);
  {
    dim3 gf((NN + 5) / 6, 2);
    k_fused<16, 6, 2><<<gf, TPB, 0, stream>>>(
        row_off, colpos, hg, Vp + 65536, xpB, Bb, msg0, msg1, msg2, msg3);
  }
  // layer 2 (DP=16 -> D=16)
  k_aggprep<16, 16, 2><<<(NN + 31) / 32, TPB, 0, stream>>>(
      col_off, msg0, msg1, msg2, msg3, rootB, xpB,
      L[2].pw, L[2].pb, L[2].rw, L[2].cb, L[2].eb2, xpA, rootA, Bb);
  k_h<<<HB, TPB, 0, stream>>>(eid_row, ea, L[2].ew1, L[2].eb1, hg);
  {
    dim3 gf((NN + 5) / 6, 2);
    k_fused<16, 6, 2><<<gf, TPB, 0, stream>>>(
        row_off, colpos, hg, Vp + 81920, xpA, Bb, msg0, msg1, msg2, msg3);
  }
  // layer 3 (DP=16 -> D=16)
  k_aggprep<16, 16, 2><<<(NN + 31) / 32, TPB, 0, stream>>>(
      col_off, msg0, msg1, msg2, msg3, rootA, xpA,
      L[3].pw, L[3].pb, L[3].rw, L[3].cb, L[3].eb2, xpB, rootB, Bb);
  k_h<<<HB, TPB, 0, stream>>>(eid_row, ea, L[3].ew1, L[3].eb1, hg);
  {
    dim3 gf((NN + 5) / 6, 2);
    k_fused<16, 6, 2><<<gf, TPB, 0, stream>>>(
        row_off, colpos, hg, Vp + 98304, xpB, Bb, msg0, msg1, msg2, msg3);
  }
  // final aggregation + edge MLP
  k_agg<16, 2><<<(NN + 31) / 32, TPB, 0, stream>>>(
      col_off, msg0, msg1, rootB, xpB, xfin);
  k_final<<<(NE + TPB - 1) / TPB, TPB, 0, stream>>>(ei, xfin, mw0, mb0, mw1, mb1, out);
}

// Round 20
// 298.490 us; speedup vs baseline: 1.2736x; 1.2736x over previous
//
#include <hip/hip_runtime.h>

#define NN 10000
#define NE 160000
static constexpr int TPB = 256;
static constexpr int SCAN_T = 1024;

typedef unsigned int uint32;

static __device__ __forceinline__ ushort f2bf(float f) {
  uint32 u = __float_as_uint(f);
  u += 0x7fff + ((u >> 16) & 1);   // round-to-nearest-even
  return (ushort)(u >> 16);
}
static __device__ __forceinline__ uint32 pk2bf(float a, float b) {
  return (uint32)f2bf(a) | ((uint32)f2bf(b) << 16);
}
static __device__ __forceinline__ float bflo(uint32 u) {
  return __uint_as_float(u << 16);
}
static __device__ __forceinline__ float bfhi(uint32 u) {
  return __uint_as_float(u & 0xffff0000u);
}
// acc += a.lo*b.lo + a.hi*b.hi  (packed bf16 pairs, f32 accumulate)
static __device__ __forceinline__ void dot2bf(float& acc, uint32 a, uint32 b) {
  asm("v_dot2_f32_bf16 %0, %1, %2, %0" : "+v"(acc) : "v"(a), "v"(b));
}

// ---------------- sort / CSR build ----------------

// cnt = [row counts (NN) | col counts (NN)] contiguous
__global__ void k_count(const int* __restrict__ ei, int* __restrict__ cnt) {
  int e = blockIdx.x * TPB + threadIdx.x;
  if (e >= NE) return;
  atomicAdd(&cnt[ei[e]], 1);
  atomicAdd(&cnt[NN + ei[NE + e]], 1);
}

// 16-wave block scan: block 0 -> row CSR, block 1 -> col CSR.
__global__ void __launch_bounds__(SCAN_T)
k_scan2(const int* __restrict__ cnt_all, int* __restrict__ off_r, int* __restrict__ cur_r,
        int* __restrict__ off_c, int* __restrict__ cur_c) {
  const int* cnt = (blockIdx.x == 0) ? cnt_all : cnt_all + NN;
  int* off = (blockIdx.x == 0) ? off_r : off_c;
  int* cur = (blockIdx.x == 0) ? cur_r : cur_c;
  __shared__ int s_wave[16];
  __shared__ int s_carry;
  int tid = threadIdx.x;
  int lane = tid & 63, wid = tid >> 6;
  if (tid == 0) s_carry = 0;
  __syncthreads();
  for (int base = 0; base < NN; base += SCAN_T) {
    int i = base + tid;
    int v = (i < NN) ? cnt[i] : 0;
    int s = v;
    #pragma unroll
    for (int d = 1; d < 64; d <<= 1) {
      int t = __shfl_up(s, d, 64);
      if (lane >= d) s += t;
    }
    if (lane == 63) s_wave[wid] = s;
    __syncthreads();
    if (wid == 0 && lane < 16) {
      int ws = s_wave[lane];
      #pragma unroll
      for (int d = 1; d < 16; d <<= 1) {
        int t = __shfl_up(ws, d, 64);
        if (lane >= d) ws += t;
      }
      s_wave[lane] = ws;   // inclusive wave-sum scan
    }
    __syncthreads();
    int waveoff = (wid > 0) ? s_wave[wid - 1] : 0;
    int excl = s_carry + waveoff + s - v;
    if (i < NN) { off[i] = excl; cur[i] = excl; }
    __syncthreads();   // all reads of s_carry/s_wave done
    if (tid == 0) s_carry += s_wave[15];
    __syncthreads();
  }
  if (tid == 0) off[NN] = s_carry;
}

__global__ void k_fill_row(const int* __restrict__ ei, int* __restrict__ cur_row,
                           int* __restrict__ eid_row) {
  int e = blockIdx.x * TPB + threadIdx.x;
  if (e >= NE) return;
  int r = ei[e];
  int p = atomicAdd(&cur_row[r], 1);
  eid_row[p] = e;
}

// colpos[s] = position of sorted-slot s in col-sorted order (direct, no inverse pass)
__global__ void k_fill_colpos(const int* __restrict__ ei, const int* __restrict__ eid_row,
                              int* __restrict__ cur_col, int* __restrict__ colpos) {
  int s = blockIdx.x * TPB + threadIdx.x;
  if (s >= NE) return;
  int e = eid_row[s];
  int c = ei[NE + e];
  int p = atomicAdd(&cur_col[c], 1);
  colpos[s] = p;
}

// ---------------- per-layer kernels ----------------

// xp = x@pw^T + pb ; root = xp@rw^T + cb ; B[n,o] = sum_i xp[i]*eb2[i*D+o]
template<int DIN, int D>
__global__ void __launch_bounds__(TPB)
k_nodeprep(const float* __restrict__ x, const float* __restrict__ pw, const float* __restrict__ pb,
           const float* __restrict__ rw, const float* __restrict__ cb, const float* __restrict__ eb2,
           float* __restrict__ xp, float* __restrict__ root, float* __restrict__ Bb) {
  __shared__ float s_pw[D * DIN], s_rw[D * D], s_eb2[D * D], s_pb[D], s_cb[D];
  for (int t = threadIdx.x; t < D * DIN; t += TPB) s_pw[t] = pw[t];
  for (int t = threadIdx.x; t < D * D; t += TPB) { s_rw[t] = rw[t]; s_eb2[t] = eb2[t]; }
  for (int t = threadIdx.x; t < D; t += TPB) { s_pb[t] = pb[t]; s_cb[t] = cb[t]; }
  __syncthreads();
  int n = blockIdx.x * TPB + threadIdx.x;
  if (n >= NN) return;
  float xv[DIN];
  const float4* x4 = (const float4*)(x + (size_t)n * DIN);
  #pragma unroll
  for (int i = 0; i < DIN / 4; i++) {
    float4 v = x4[i];
    xv[4*i+0] = v.x; xv[4*i+1] = v.y; xv[4*i+2] = v.z; xv[4*i+3] = v.w;
  }
  float xpv[D];
  #pragma unroll
  for (int o = 0; o < D; o++) {
    float a = s_pb[o];
    #pragma unroll
    for (int i = 0; i < DIN; i++) a = fmaf(s_pw[o*DIN + i], xv[i], a);
    xpv[o] = a;
    xp[(size_t)n*D + o] = a;
  }
  #pragma unroll
  for (int o = 0; o < D; o++) {
    float a = s_cb[o];
    #pragma unroll
    for (int i = 0; i < D; i++) a = fmaf(s_rw[o*D + i], xpv[i], a);
    root[(size_t)n*D + o] = a;
  }
  #pragma unroll
  for (int o = 0; o < D; o++) {
    float a = 0.f;
    #pragma unroll
    for (int i = 0; i < D; i++) a = fmaf(xpv[i], s_eb2[i*D + o], a);
    Bb[(size_t)n*D + o] = a;
  }
}

// Fused agg + next-layer nodeprep (layers 1..3), packed-bf16 msg input.
template<int DP, int D>
__global__ void __launch_bounds__(TPB)
k_aggprep(const int* __restrict__ col_off,
          const uint32* __restrict__ msg0p, const uint32* __restrict__ msg1p,
          const float* __restrict__ root_prev, const float* __restrict__ xp_prev,
          const float* __restrict__ pw, const float* __restrict__ pb,
          const float* __restrict__ rw, const float* __restrict__ cb,
          const float* __restrict__ eb2,
          float* __restrict__ xp, float* __restrict__ root, float* __restrict__ Bb) {
  constexpr int W = DP / 2;      // packed words per edge
  constexpr int NB = TPB / W;    // nodes per block (16 for DP=32, 32 for DP=16)
  __shared__ float s_x[NB][DP];
  __shared__ float s_xpv[NB][D];
  __shared__ float s_pw[D * DP], s_rw[D * D], s_eb2[D * D], s_pb[D], s_cb[D];
  int tid = threadIdx.x;
  for (int t = tid; t < D * DP; t += TPB) s_pw[t] = pw[t];
  for (int t = tid; t < D * D; t += TPB) { s_rw[t] = rw[t]; s_eb2[t] = eb2[t]; }
  for (int t = tid; t < D; t += TPB) { s_pb[t] = pb[t]; s_cb[t] = cb[t]; }
  int g = tid / W, o2 = tid % W;
  int n = blockIdx.x * NB + g;
  if (n < NN) {
    int p0 = col_off[n], p1 = col_off[n + 1];
    float ax = 0.f, ay = 0.f;
    for (int p = p0; p < p1; p++) {
      uint32 w0 = msg0p[(size_t)p * W + o2];
      uint32 w1 = msg1p[(size_t)p * W + o2];
      ax += bflo(w0) + bflo(w1);
      ay += bfhi(w0) + bfhi(w1);
    }
    float deg = (p1 > p0) ? (float)(p1 - p0) : 1.f;
    float2 rp = *(const float2*)(root_prev + (size_t)n * DP + 2 * o2);
    float2 xq = *(const float2*)(xp_prev + (size_t)n * DP + 2 * o2);
    float c0 = ax / deg + rp.x, c1 = ay / deg + rp.y;
    s_x[g][2 * o2]     = (c0 > 0.f ? c0 : 0.f) + xq.x;
    s_x[g][2 * o2 + 1] = (c1 > 0.f ? c1 : 0.f) + xq.y;
  }
  __syncthreads();
  for (int t = tid; t < NB * D; t += TPB) {
    int g2 = t / D, o = t % D;
    int n2 = blockIdx.x * NB + g2;
    if (n2 < NN) {
      float a = s_pb[o];
      #pragma unroll
      for (int i = 0; i < DP; i++) a = fmaf(s_pw[o * DP + i], s_x[g2][i], a);
      s_xpv[g2][o] = a;
      xp[(size_t)n2 * D + o] = a;
    }
  }
  __syncthreads();
  for (int t = tid; t < NB * D; t += TPB) {
    int g2 = t / D, o = t % D;
    int n2 = blockIdx.x * NB + g2;
    if (n2 < NN) {
      float r2 = s_cb[o], b2 = 0.f;
      #pragma unroll
      for (int i = 0; i < D; i++) {
        r2 = fmaf(s_rw[o * D + i], s_xpv[g2][i], r2);
        b2 = fmaf(s_xpv[g2][i], s_eb2[i * D + o], b2);
      }
      root[(size_t)n2 * D + o] = r2;
      Bb[(size_t)n2 * D + o] = b2;
    }
  }
}

// All four layers' V transposes in one dispatch.
// Layout (words): l0 @0 (65536, D=32), l1 @65536, l2 @81920, l3 @98304 (16384 each, D=16)
__global__ void k_trans_all(const float* __restrict__ e0, const float* __restrict__ e1,
                            const float* __restrict__ e2, const float* __restrict__ e3,
                            uint32* __restrict__ Vp) {
  int t = blockIdx.x * TPB + threadIdx.x;
  const float* ew2; uint32* dst; int D, loc;
  if (t < 65536)       { ew2 = e0; dst = Vp;         D = 32; loc = t; }
  else if (t < 81920)  { ew2 = e1; dst = Vp + 65536; D = 16; loc = t - 65536; }
  else if (t < 98304)  { ew2 = e2; dst = Vp + 81920; D = 16; loc = t - 81920; }
  else if (t < 114688) { ew2 = e3; dst = Vp + 98304; D = 16; loc = t - 98304; }
  else return;
  int COLS = D * 128;
  int i2 = loc / COLS;
  int r = loc - i2 * COLS;
  int w = r >> 1, p = r & 1;
  int k2 = w / D, o = w - k2 * D;
  int k = 2 * k2 + p;
  float lo = ew2[((size_t)((2 * i2) * D + o)) * 128 + k];
  float hi = ew2[((size_t)((2 * i2 + 1) * D + o)) * 128 + k];
  dst[loc] = pk2bf(lo, hi);
}

// Fused, split-k over blockIdx.y (half = 0/1).
// Phase B: half U-rows (packed bf16 k-pairs, word[k2loc*D+o], row stride UP) into LDS.
// Phase C: h (half k-range) via dot2 -> packed k-pairs; partial msg = h.U (+B if half 0)
//          scattered bf16-packed to msgHp[colpos[s]] (col-sorted for sequential agg).
template<int D, int G>
__global__ void __launch_bounds__(TPB)
k_fused(const int* __restrict__ eid_row, const int* __restrict__ row_off,
        const int* __restrict__ colpos,
        const float* __restrict__ ea, const float* __restrict__ ew1,
        const float* __restrict__ eb1, const uint32* __restrict__ Vp,
        const float* __restrict__ xp, const float* __restrict__ Bb,
        uint32* __restrict__ msg0p, uint32* __restrict__ msg1p) {
  constexpr int OQ = D / 4;            // threads per edge
  constexpr int EB = TPB / OQ;         // edges per inner iteration
  constexpr int COLS = D * 128;
  constexpr int UW = COLS / 2;         // u32 words per full U-row
  constexpr int UH = UW / 2;           // words per half U-row
  constexpr int UP = UH + 4;           // padded row stride (bank stagger, 16B-aligned)
  constexpr int CT = UH / TPB;         // words per thread (4 for D32, 2 for D16)

  __shared__ __align__(16) uint32 s_w1tp[4 * 64];   // packed ew1 i-pairs: [i2][kloc]
  __shared__ float  s_b1[64];
  __shared__ __align__(16) uint32 s_U[G * UP];      // packed bf16 k-pairs (half)
  __shared__ __align__(16) uint32 s_hp[EB * 36];    // packed bf16 h k-pairs, stride 36 (16B-aligned)
  __shared__ __align__(16) uint32 s_eap[EB * 4];    // packed ea i-pairs
  __shared__ int    s_cp[EB];                       // col-sorted dest of each edge
  __shared__ uint32 s_xp2[G][D / 2];                // packed xp i-pairs
  __shared__ float  s_B[G * D];
  __shared__ int    s_off[G + 1];

  int tid = threadIdx.x;
  int half = blockIdx.y;
  int n0 = blockIdx.x * G;
  int GA = NN - n0; if (GA > G) GA = G;
  uint32* msgHp = half ? msg1p : msg0p;

  // ---- phase A: stage weights (this k-half) + per-node vectors ----
  for (int t = tid; t < 4 * 64; t += TPB) {
    int i2 = t >> 6, kloc = t & 63;
    int k = half * 64 + kloc;
    s_w1tp[t] = pk2bf(ew1[k * 8 + 2 * i2], ew1[k * 8 + 2 * i2 + 1]);
  }
  for (int t = tid; t < 64; t += TPB) s_b1[t] = eb1[half * 64 + t];
  for (int t = tid; t < G * (D / 2); t += TPB) {
    int g = t / (D / 2), i2 = t % (D / 2);
    if (g < GA) {
      float2 v = *(const float2*)(xp + (size_t)(n0 + g) * D + 2 * i2);
      s_xp2[g][i2] = pk2bf(v.x, v.y);
    } else {
      s_xp2[g][i2] = 0;
    }
  }
  for (int t = tid; t < G * D; t += TPB) {
    int g = t / D, i = t % D;
    s_B[t] = (g < GA && half == 0) ? Bb[(size_t)(n0 + g) * D + i] : 0.f;
  }
  if (tid <= GA) s_off[tid] = row_off[n0 + tid];
  __syncthreads();

  // ---- phase B: half U-rows into LDS via dot2 (CT words x G nodes / thread) ----
  {
    const uint2* Vp2 = (const uint2*)Vp;   // [i2][w] -> {p=0 word, p=1 word}
    float accLo[G][CT], accHi[G][CT];
    #pragma unroll
    for (int g = 0; g < G; g++)
      #pragma unroll
      for (int j = 0; j < CT; j++) { accLo[g][j] = 0.f; accHi[g][j] = 0.f; }
    #pragma unroll 2
    for (int i2 = 0; i2 < D / 2; i2++) {
      uint2 vv[CT];
      #pragma unroll
      for (int j = 0; j < CT; j++)
        vv[j] = Vp2[(size_t)i2 * UW + half * UH + j * TPB + tid];
      #pragma unroll
      for (int g = 0; g < G; g++) {
        uint32 xg = s_xp2[g][i2];
        #pragma unroll
        for (int j = 0; j < CT; j++) {
          dot2bf(accLo[g][j], xg, vv[j].x);
          dot2bf(accHi[g][j], xg, vv[j].y);
        }
      }
    }
    #pragma unroll
    for (int g = 0; g < G; g++)
      #pragma unroll
      for (int j = 0; j < CT; j++)
        s_U[g * UP + j * TPB + tid] = pk2bf(accLo[g][j], accHi[g][j]);
  }

  // ---- phase C: edges of the group (contiguous sorted slots) ----
  int p0 = row_off[n0], p1 = row_off[n0 + GA];
  int el = tid / OQ, oq = tid % OQ;
  for (int pc = p0; pc < p1; pc += EB) {
    int cnt = p1 - pc; if (cnt > EB) cnt = EB;
    __syncthreads();   // first iter: phase A/B done; later: protect s_eap/s_hp reuse
    for (int t = tid; t < cnt * 4; t += TPB) {
      int e2 = t >> 2, i2 = t & 3;
      float2 v = *(const float2*)(ea + (size_t)eid_row[pc + e2] * 8 + 2 * i2);
      s_eap[t] = pk2bf(v.x, v.y);
    }
    for (int t = tid; t < cnt; t += TPB) s_cp[t] = colpos[pc + t];
    __syncthreads();
    // h (half k-range) packed as bf16 k-pairs via dot2
    for (int t = tid; t < cnt * 32; t += TPB) {
      int e2 = t >> 5, k2 = t & 31;
      float a0 = s_b1[2 * k2], a1 = s_b1[2 * k2 + 1];
      #pragma unroll
      for (int i2 = 0; i2 < 4; i2++) {
        uint32 ep = s_eap[e2 * 4 + i2];
        uint2 ww = *(const uint2*)(s_w1tp + i2 * 64 + 2 * k2);
        dot2bf(a0, ep, ww.x);
        dot2bf(a1, ep, ww.y);
      }
      s_hp[e2 * 36 + k2] = pk2bf(fmaxf(a0, 0.f), fmaxf(a1, 0.f));
    }
    __syncthreads();
    if (el < cnt) {
      int g = 0;
      {
        int s = pc + el;
        #pragma unroll
        for (int q = 1; q < G; q++) g += (q < GA && s >= s_off[q]) ? 1 : 0;
      }
      const uint32* up = s_U + g * UP + oq * 4;
      const uint32* hp = s_hp + el * 36;
      float a0 = 0.f, a1 = 0.f, a2 = 0.f, a3 = 0.f;
      #pragma unroll
      for (int k8 = 0; k8 < 8; k8++) {
        uint4 hw = *(const uint4*)(hp + 4 * k8);
        uint4 u0 = *(const uint4*)(up + (4 * k8 + 0) * D);
        uint4 u1 = *(const uint4*)(up + (4 * k8 + 1) * D);
        uint4 u2 = *(const uint4*)(up + (4 * k8 + 2) * D);
        uint4 u3 = *(const uint4*)(up + (4 * k8 + 3) * D);
        dot2bf(a0, hw.x, u0.x); dot2bf(a1, hw.x, u0.y); dot2bf(a2, hw.x, u0.z); dot2bf(a3, hw.x, u0.w);
        dot2bf(a0, hw.y, u1.x); dot2bf(a1, hw.y, u1.y); dot2bf(a2, hw.y, u1.z); dot2bf(a3, hw.y, u1.w);
        dot2bf(a0, hw.z, u2.x); dot2bf(a1, hw.z, u2.y); dot2bf(a2, hw.z, u2.z); dot2bf(a3, hw.z, u2.w);
        dot2bf(a0, hw.w, u3.x); dot2bf(a1, hw.w, u3.y); dot2bf(a2, hw.w, u3.z); dot2bf(a3, hw.w, u3.w);
      }
      float4 b = ((const float4*)(s_B + g * D))[oq];
      uint2 om;
      om.x = pk2bf(a0 + b.x, a1 + b.y);
      om.y = pk2bf(a2 + b.z, a3 + b.w);
      ((uint2*)(msgHp + (size_t)s_cp[el] * (D / 2)))[oq] = om;
    }
  }
}

// last-layer aggregation (packed msg in, f32 x out for the final edge MLP)
template<int D>
__global__ void __launch_bounds__(TPB)
k_agg(const int* __restrict__ col_off,
      const uint32* __restrict__ msg0p, const uint32* __restrict__ msg1p,
      const float* __restrict__ root, const float* __restrict__ xp,
      float* __restrict__ xout) {
  constexpr int W = D / 2;
  constexpr int GP = TPB / W;
  int g = threadIdx.x / W, o2 = threadIdx.x % W;
  int n = blockIdx.x * GP + g;
  if (n >= NN) return;
  int p0 = col_off[n], p1 = col_off[n + 1];
  float ax = 0.f, ay = 0.f;
  for (int p = p0; p < p1; p++) {
    uint32 w0 = msg0p[(size_t)p * W + o2];
    uint32 w1 = msg1p[(size_t)p * W + o2];
    ax += bflo(w0) + bflo(w1);
    ay += bfhi(w0) + bfhi(w1);
  }
  float deg = (p1 > p0) ? (float)(p1 - p0) : 1.f;
  float2 rp = *(const float2*)(root + (size_t)n * D + 2 * o2);
  float2 xq = *(const float2*)(xp + (size_t)n * D + 2 * o2);
  float c0 = ax / deg + rp.x, c1 = ay / deg + rp.y;
  xout[(size_t)n * D + 2 * o2]     = (c0 > 0.f ? c0 : 0.f) + xq.x;
  xout[(size_t)n * D + 2 * o2 + 1] = (c1 > 0.f ? c1 : 0.f) + xq.y;
}

// final edge MLP: out = relu((x[row]+x[col]) @ mw0^T + mb0) @ mw1^T + mb1
__global__ void __launch_bounds__(TPB)
k_final(const int* __restrict__ ei, const float* __restrict__ x,
        const float* __restrict__ mw0, const float* __restrict__ mb0,
        const float* __restrict__ mw1, const float* __restrict__ mb1,
        float* __restrict__ out) {
  __shared__ float s_w0[256], s_b0[16], s_w1[16], s_b1;
  for (int t = threadIdx.x; t < 256; t += TPB) s_w0[t] = mw0[t];
  if (threadIdx.x < 16) { s_b0[threadIdx.x] = mb0[threadIdx.x]; s_w1[threadIdx.x] = mw1[threadIdx.x]; }
  if (threadIdx.x == 0) s_b1 = mb1[0];
  __syncthreads();
  int e = blockIdx.x * TPB + threadIdx.x;
  if (e >= NE) return;
  int r = ei[e], c = ei[NE + e];
  const float4* xr4 = (const float4*)(x + (size_t)r * 16);
  const float4* xc4 = (const float4*)(x + (size_t)c * 16);
  float er[16];
  #pragma unroll
  for (int q = 0; q < 4; q++) {
    float4 vr = xr4[q], vc = xc4[q];
    er[4*q+0] = vr.x + vc.x; er[4*q+1] = vr.y + vc.y;
    er[4*q+2] = vr.z + vc.z; er[4*q+3] = vr.w + vc.w;
  }
  float o = s_b1;
  #pragma unroll
  for (int j = 0; j < 16; j++) {
    float t = s_b0[j];
    #pragma unroll
    for (int k = 0; k < 16; k++) t = fmaf(er[k], s_w0[j * 16 + k], t);
    t = fmaxf(t, 0.f);
    o = fmaf(t, s_w1[j], o);
  }
  out[e] = o;
}

// ---------------- host side ----------------

struct LayerPtrs {
  const float *pw, *pb, *ew1, *eb1, *ew2, *eb2, *rw, *cb;
};

extern "C" void kernel_launch(void* const* d_in, const int* in_sizes, int n_in,
                              void* d_out, int out_size, void* d_ws, size_t ws_size,
                              hipStream_t stream) {
  (void)in_sizes; (void)n_in; (void)out_size; (void)ws_size;
  const float* x0 = (const float*)d_in[0];
  const float* ea = (const float*)d_in[1];
  const int* ei = (const int*)d_in[2];
  LayerPtrs L[4];
  for (int l = 0; l < 4; l++) {
    L[l].pw  = (const float*)d_in[3 + 8 * l];
    L[l].pb  = (const float*)d_in[4 + 8 * l];
    L[l].ew1 = (const float*)d_in[5 + 8 * l];
    L[l].eb1 = (const float*)d_in[6 + 8 * l];
    L[l].ew2 = (const float*)d_in[7 + 8 * l];
    L[l].eb2 = (const float*)d_in[8 + 8 * l];
    L[l].rw  = (const float*)d_in[9 + 8 * l];
    L[l].cb  = (const float*)d_in[10 + 8 * l];
  }
  const float* mw0 = (const float*)d_in[35];
  const float* mb0 = (const float*)d_in[36];
  const float* mw1 = (const float*)d_in[37];
  const float* mb1 = (const float*)d_in[38];
  float* out = (float*)d_out;

  char* w = (char*)d_ws;
  size_t off = 0;
  auto alloc = [&](size_t b) -> void* {
    void* p = w + off;
    off = (off + b + 255) & ~(size_t)255;
    return p;
  };
  int* cnt      = (int*)alloc(sizeof(int) * 2 * NN);   // [row | col]
  int* row_off  = (int*)alloc(sizeof(int) * (NN + 1));
  int* col_off  = (int*)alloc(sizeof(int) * (NN + 1));
  int* cur_row  = (int*)alloc(sizeof(int) * NN);
  int* cur_col  = (int*)alloc(sizeof(int) * NN);
  int* eid_row  = (int*)alloc(sizeof(int) * NE);
  int* colpos   = (int*)alloc(sizeof(int) * NE);
  float* xpA   = (float*)alloc(sizeof(float) * NN * 32);
  float* xpB   = (float*)alloc(sizeof(float) * NN * 32);
  float* rootA = (float*)alloc(sizeof(float) * NN * 32);
  float* rootB = (float*)alloc(sizeof(float) * NN * 32);
  float* Bb    = (float*)alloc(sizeof(float) * NN * 32);
  uint32* msg0p = (uint32*)alloc(sizeof(uint32) * NE * 16);
  uint32* msg1p = (uint32*)alloc(sizeof(uint32) * NE * 16);
  float* xfin  = (float*)alloc(sizeof(float) * NN * 16);
  uint32* Vp   = (uint32*)alloc(sizeof(uint32) * 114688);  // 448 KB, all layers

  hipMemsetAsync(cnt, 0, sizeof(int) * 2 * NN, stream);
  k_count<<<(NE + TPB - 1) / TPB, TPB, 0, stream>>>(ei, cnt);
  k_scan2<<<2, SCAN_T, 0, stream>>>(cnt, row_off, cur_row, col_off, cur_col);
  k_fill_row<<<(NE + TPB - 1) / TPB, TPB, 0, stream>>>(ei, cur_row, eid_row);
  k_fill_colpos<<<(NE + TPB - 1) / TPB, TPB, 0, stream>>>(ei, eid_row, cur_col, colpos);
  k_trans_all<<<(114688 + TPB - 1) / TPB, TPB, 0, stream>>>(
      L[0].ew2, L[1].ew2, L[2].ew2, L[3].ew2, Vp);

  // layer 0 (DIN=16, D=32)
  k_nodeprep<16, 32><<<(NN + TPB - 1) / TPB, TPB, 0, stream>>>(
      x0, L[0].pw, L[0].pb, L[0].rw, L[0].cb, L[0].eb2, xpA, rootA, Bb);
  {
    dim3 gf((NN + 5) / 6, 2);
    k_fused<32, 6><<<gf, TPB, 0, stream>>>(
        eid_row, row_off, colpos, ea, L[0].ew1, L[0].eb1, Vp, xpA, Bb, msg0p, msg1p);
  }
  // layer 1 (DP=32 -> D=16)
  k_aggprep<32, 16><<<(NN + 15) / 16, TPB, 0, stream>>>(
      col_off, msg0p, msg1p, rootA, xpA,
      L[1].pw, L[1].pb, L[1].rw, L[1].cb, L[1].eb2, xpB, rootB, Bb);
  {
    dim3 gf((NN + 5) / 6, 2);
    k_fused<16, 6><<<gf, TPB, 0, stream>>>(
        eid_row, row_off, colpos, ea, L[1].ew1, L[1].eb1, Vp + 65536, xpB, Bb, msg0p, msg1p);
  }
  // layer 2 (DP=16 -> D=16)
  k_aggprep<16, 16><<<(NN + 31) / 32, TPB, 0, stream>>>(
      col_off, msg0p, msg1p, rootB, xpB,
      L[2].pw, L[2].pb, L[2].rw, L[2].cb, L[2].eb2, xpA, rootA, Bb);
  {
    dim3 gf((NN + 5) / 6, 2);
    k_fused<16, 6><<<gf, TPB, 0, stream>>>(
        eid_row, row_off, colpos, ea, L[2].ew1, L[2].eb1, Vp + 81920, xpA, Bb, msg0p, msg1p);
  }
  // layer 3 (DP=16 -> D=16)
  k_aggprep<16, 16><<<(NN + 31) / 32, TPB, 0, stream>>>(
      col_off, msg0p, msg1p, rootA, xpA,
      L[3].pw, L[3].pb, L[3].rw, L[3].cb, L[3].eb2, xpB, rootB, Bb);
  {
    dim3 gf((NN + 5) / 6, 2);
    k_fused<16, 6><<<gf, TPB, 0, stream>>>(
        eid_row, row_off, colpos, ea, L[3].ew1, L[3].eb1, Vp + 98304, xpB, Bb, msg0p, msg1p);
  }
  // final aggregation + edge MLP
  k_agg<16><<<(NN + 31) / 32, TPB, 0, stream>>>(
      col_off, msg0p, msg1p, rootB, xpB, xfin);
  k_final<<<(NE + TPB - 1) / TPB, TPB, 0, stream>>>(ei, xfin, mw0, mb0, mw1, mb1, out);
}